// Round 5
// baseline (107.931 us; speedup 1.0000x reference)
//
#include <hip/hip_runtime.h>

#define LOG2E 1.4426950408889634f
#define K_SCALE 2.8853900817779268f   // 2*log2(e)

typedef __attribute__((ext_vector_type(8))) short bf16x8;
typedef __attribute__((ext_vector_type(4))) float f32x4;

constexpr int Bn = 4, LXn = 384, LYn = 384, Hn = 256, Fn = 512;

__device__ inline unsigned short bf16rn(float f) {
  unsigned u = __builtin_bit_cast(unsigned, f);
  u += 0x7fff + ((u >> 16) & 1);             // round-to-nearest-even
  return (unsigned short)(u >> 16);
}
__device__ inline float bf16tof(unsigned short h) {
  return __builtin_bit_cast(float, (unsigned)h << 16);
}

// ---------------------------------------------------------------- kernel 1
// (R12 gemm5 — correctness proven; single barrier per kc via LDS dbuf)
// blocks [0,192):   ey tiles 32x64  = exp2(-K * y.Wm^T)
// blocks [192,384): exT tiles 32x64 = exp2(+K * Wm.x^T)
// blocks [384,576): transpose+split x -> xTh/xTl[b][f][l]
__global__ __launch_bounds__(256) void gemm5(
    const float* __restrict__ x, const float* __restrict__ y,
    const float* __restrict__ Wm, float* __restrict__ ey, float* __restrict__ exT,
    unsigned short* __restrict__ xTh, unsigned short* __restrict__ xTl)
{
  __shared__ char smem[55296];
  const int tid = threadIdx.x;
  const int bid = blockIdx.x;

  if (bid >= 384) {                       // ---- transpose/split path ----
    float* T = (float*)smem;              // [64][65]
    const int pid = bid - 384;
    const int b = pid / 48, t = pid % 48;
    const int l0 = (t / 8) * 64, f0 = (t % 8) * 64;
    const int r = tid >> 2, cq = (tid & 3) * 16;
    const float* xp = x + ((size_t)(b * LXn + l0 + r)) * Fn + f0 + cq;
    #pragma unroll
    for (int q = 0; q < 4; ++q) {
      float4 v = *(const float4*)(xp + q * 4);
      T[r * 65 + cq + q * 4 + 0] = v.x; T[r * 65 + cq + q * 4 + 1] = v.y;
      T[r * 65 + cq + q * 4 + 2] = v.z; T[r * 65 + cq + q * 4 + 3] = v.w;
    }
    __syncthreads();
    const int fr = tid >> 2, lq = (tid & 3) * 16;
    unsigned short hi[16], lo[16];
    #pragma unroll
    for (int i = 0; i < 16; ++i) {
      float v = T[(lq + i) * 65 + fr];
      hi[i] = bf16rn(v);
      lo[i] = bf16rn(v - bf16tof(hi[i]));
    }
    size_t o = ((size_t)(b * Fn + f0 + fr)) * LXn + l0 + lq;
    *(uint4*)&xTh[o] = *(uint4*)&hi[0]; *(uint4*)&xTh[o + 8] = *(uint4*)&hi[8];
    *(uint4*)&xTl[o] = *(uint4*)&lo[0]; *(uint4*)&xTl[o + 8] = *(uint4*)&lo[8];
    return;
  }

  // ---- MFMA GEMM path, 32x64 tile, double-buffered ----
  unsigned short* S0 = (unsigned short*)smem;

  const float *Ap, *Bp; float ksc; bool jobA;
  int m0, n0;
  if (bid < 192) { jobA = true;  m0 = (bid % 48) * 32; n0 = (bid / 48) * 64;
                   Ap = y;  Bp = Wm; ksc = -K_SCALE; }
  else { int t = bid - 192; jobA = false; m0 = (t % 8) * 32; n0 = (t / 8) * 64;
                   Ap = Wm; Bp = x;  ksc =  K_SCALE; }

  const int rA = tid >> 3, kA = (tid & 7) * 8;    // A staging: 32 rows x 64 k
  const int rB = tid >> 2, kB = (tid & 3) * 16;   // B staging: 64 rows x 64 k
  const int w = tid >> 6, lane = tid & 63, quad = lane >> 4, l15 = lane & 15;
  const int mo = (w & 1) * 16, no = (w >> 1) * 32;   // wave: 16x32 out
  f32x4 acc[2] = {};

  const float* apt = Ap + ((size_t)(m0 + rA)) * Fn + kA;
  const float* bpt = Bp + ((size_t)(n0 + rB)) * Fn + kB;
  float4 aR0 = *(const float4*)(apt),     aR1 = *(const float4*)(apt + 4);
  float4 bR0 = *(const float4*)(bpt),     bR1 = *(const float4*)(bpt + 4);
  float4 bR2 = *(const float4*)(bpt + 8), bR3 = *(const float4*)(bpt + 12);

  // preload buffer 0
  {
    unsigned short* D = S0;
    float av[8] = {aR0.x, aR0.y, aR0.z, aR0.w, aR1.x, aR1.y, aR1.z, aR1.w};
    unsigned short hi[16], lo[16];
    #pragma unroll
    for (int i = 0; i < 8; ++i) { hi[i] = bf16rn(av[i]); lo[i] = bf16rn(av[i] - bf16tof(hi[i])); }
    *(uint4*)&D[rA * 72 + kA] = *(uint4*)&hi[0];
    *(uint4*)&D[2304 + rA * 72 + kA] = *(uint4*)&lo[0];
    float bv[16] = {bR0.x, bR0.y, bR0.z, bR0.w, bR1.x, bR1.y, bR1.z, bR1.w,
                    bR2.x, bR2.y, bR2.z, bR2.w, bR3.x, bR3.y, bR3.z, bR3.w};
    #pragma unroll
    for (int i = 0; i < 16; ++i) { hi[i] = bf16rn(bv[i]); lo[i] = bf16rn(bv[i] - bf16tof(hi[i])); }
    *(uint4*)&D[4608 + rB * 72 + kB] = *(uint4*)&hi[0];
    *(uint4*)&D[4608 + rB * 72 + kB + 8] = *(uint4*)&hi[8];
    *(uint4*)&D[9216 + rB * 72 + kB] = *(uint4*)&lo[0];
    *(uint4*)&D[9216 + rB * 72 + kB + 8] = *(uint4*)&lo[8];
  }
  __syncthreads();

  for (int kc = 0; kc < Fn; kc += 64) {
    const int cur = (kc >> 6) & 1;
    unsigned short* Sc = S0 + cur * 13824;
    unsigned short* Sn = S0 + (cur ^ 1) * 13824;
    const bool more = (kc + 64) < Fn;
    if (more) {                           // prefetch next tile into VGPRs
      aR0 = *(const float4*)(apt + kc + 64);     aR1 = *(const float4*)(apt + kc + 68);
      bR0 = *(const float4*)(bpt + kc + 64);     bR1 = *(const float4*)(bpt + kc + 68);
      bR2 = *(const float4*)(bpt + kc + 72);     bR3 = *(const float4*)(bpt + kc + 76);
    }
    #pragma unroll
    for (int ko = 0; ko < 64; ko += 32) {
      const int ra = (mo + l15) * 72 + ko + quad * 8;
      bf16x8 a_h = *(const bf16x8*)&Sc[ra];
      bf16x8 a_l = *(const bf16x8*)&Sc[2304 + ra];
      #pragma unroll
      for (int nj = 0; nj < 2; ++nj) {
        const int rb = (no + nj * 16 + l15) * 72 + ko + quad * 8;
        bf16x8 b_h = *(const bf16x8*)&Sc[4608 + rb];
        bf16x8 b_l = *(const bf16x8*)&Sc[9216 + rb];
        acc[nj] = __builtin_amdgcn_mfma_f32_16x16x32_bf16(a_h, b_h, acc[nj], 0, 0, 0);
        acc[nj] = __builtin_amdgcn_mfma_f32_16x16x32_bf16(a_l, b_h, acc[nj], 0, 0, 0);
        acc[nj] = __builtin_amdgcn_mfma_f32_16x16x32_bf16(a_h, b_l, acc[nj], 0, 0, 0);
      }
    }
    if (more) {                           // convert + store into idle buffer
      float av[8] = {aR0.x, aR0.y, aR0.z, aR0.w, aR1.x, aR1.y, aR1.z, aR1.w};
      unsigned short hi[16], lo[16];
      #pragma unroll
      for (int i = 0; i < 8; ++i) { hi[i] = bf16rn(av[i]); lo[i] = bf16rn(av[i] - bf16tof(hi[i])); }
      *(uint4*)&Sn[rA * 72 + kA] = *(uint4*)&hi[0];
      *(uint4*)&Sn[2304 + rA * 72 + kA] = *(uint4*)&lo[0];
      float bv[16] = {bR0.x, bR0.y, bR0.z, bR0.w, bR1.x, bR1.y, bR1.z, bR1.w,
                      bR2.x, bR2.y, bR2.z, bR2.w, bR3.x, bR3.y, bR3.z, bR3.w};
      #pragma unroll
      for (int i = 0; i < 16; ++i) { hi[i] = bf16rn(bv[i]); lo[i] = bf16rn(bv[i] - bf16tof(hi[i])); }
      *(uint4*)&Sn[4608 + rB * 72 + kB] = *(uint4*)&hi[0];
      *(uint4*)&Sn[4608 + rB * 72 + kB + 8] = *(uint4*)&hi[8];
      *(uint4*)&Sn[9216 + rB * 72 + kB] = *(uint4*)&lo[0];
      *(uint4*)&Sn[9216 + rB * 72 + kB + 8] = *(uint4*)&lo[8];
    }
    __syncthreads();                      // single barrier per kc
  }
  #pragma unroll
  for (int nj = 0; nj < 2; ++nj)
    #pragma unroll
    for (int rr = 0; rr < 4; ++rr) {
      int row = m0 + mo + quad * 4 + rr;
      int col = n0 + no + nj * 16 + l15;
      float val = __builtin_amdgcn_exp2f(ksc * acc[nj][rr]);
      if (jobA) ey[(size_t)row * Hn + col] = val;
      else {
        int bb = col / LXn, l = col % LXn;
        exT[(size_t)bb * Hn * LXn + (size_t)row * LXn + l] = val;
      }
    }
}

// ---------------------------------------------------------------- kernel 2
// score_v6: NO cross-thread reduction. Thread = (lane=l, wave=3 j's); loops
// all 256 h in-register (2 LDS passes of 128 h). exT staged [h][66] (natural
// layout, 2-way banks = free); ey/vm reads are wave-uniform broadcasts.
// 3 barriers total. Writes unnormalized e (bf16) + S_part[6][b*384+j];
// qtm normalizes. Grid 4b x 6lt x 16jt = 384 blocks x 512 thr, ~60KB LDS
// -> 2 blocks/CU.
__global__ __launch_bounds__(512) void score_v6(
    const float* __restrict__ exT, const float* __restrict__ ey,
    const float* __restrict__ vm, unsigned short* __restrict__ ahi,
    float* __restrict__ S_part)
{
  __shared__ __align__(16) float EX[128 * 66];   // 33.8 KB (one h-pass)
  __shared__ __align__(16) float eyS[24 * 260];  // 25.0 KB
  __shared__ __align__(16) float vms[256];       // 1 KB

  const int tid = threadIdx.x;
  const int bid = blockIdx.x;
  const int xcd = bid & 7, r = bid >> 3;        // XCD-pinned groups
  const int gslot = r % 3, jt = r / 3;
  const int g = gslot * 8 + xcd;                // 24 (b,lt) groups
  const int b = g / 6, lt = g % 6;
  const int j0 = jt * 24, l0 = lt * 64;

  // stage ey [24][256] (pad 260) and vms = -2*vm
  #pragma unroll
  for (int u = 0; u < 3; ++u) {
    int idx = tid + u * 512;                    // [0,1536) float4s
    int j = idx >> 6, q = idx & 63;
    float4 v = *(const float4*)&ey[(size_t)(b * LYn + j0 + j) * Hn + q * 4];
    *(float4*)&eyS[j * 260 + q * 4] = v;
  }
  if (tid < 64) {
    float4 v = *(const float4*)&vm[tid * 4];
    v.x *= -2.f; v.y *= -2.f; v.z *= -2.f; v.w *= -2.f;
    *(float4*)&vms[tid * 4] = v;
  }

  const int lane = tid & 63, w = tid >> 6;      // 8 waves
  const int jw = w * 3;                         // wave's 3 j's
  float acc[3] = {0.f, 0.f, 0.f};

  for (int p = 0; p < 2; ++p) {
    __syncthreads();                            // prev compute done / entry
    #pragma unroll
    for (int u = 0; u < 4; ++u) {               // stage EX[h][l], h-pass p
      int idx = tid + u * 512;                  // [0,2048) float4s
      int h = idx >> 4, q = idx & 15;
      float4 v = *(const float4*)&exT[(size_t)b * Hn * LXn
                                      + (size_t)(p * 128 + h) * LXn + l0 + q * 4];
      *(float4*)&EX[h * 66 + q * 4] = v;
    }
    __syncthreads();
    #pragma unroll 4
    for (int k = 0; k < 32; ++k) {
      const int kg = p * 32 + k;
      float x0 = EX[(4 * k + 0) * 66 + lane];
      float x1 = EX[(4 * k + 1) * 66 + lane];
      float x2 = EX[(4 * k + 2) * 66 + lane];
      float x3 = EX[(4 * k + 3) * 66 + lane];
      float4 va = *(const float4*)&vms[kg * 4];
      #pragma unroll
      for (int jj = 0; jj < 3; ++jj) {
        float4 ya = *(const float4*)&eyS[(jw + jj) * 260 + kg * 4];
        float A = fmaf(x0, ya.x, 1.f);
        float B = fmaf(x1, ya.y, 1.f);
        float C = fmaf(x2, ya.z, 1.f);
        float D = fmaf(x3, ya.w, 1.f);
        float AB = A * B, CD = C * D;
        float n1 = fmaf(va.y, A, va.x * B);
        float n2 = fmaf(va.w, C, va.z * D);
        float num = fmaf(n2, AB, n1 * CD);
        acc[jj] = fmaf(num, __builtin_amdgcn_rcpf(AB * CD), acc[jj]);
      }
    }
  }

  // epilogue: e = exp2(s*log2e); write bf16 e; wave-reduce row partial sums
  #pragma unroll
  for (int jj = 0; jj < 3; ++jj) {
    float e = __builtin_amdgcn_exp2f(acc[jj] * LOG2E);
    ahi[(size_t)(b * LYn + j0 + jw + jj) * LXn + l0 + lane] = bf16rn(e);
    float v = e;
    #pragma unroll
    for (int off = 32; off > 0; off >>= 1) v += __shfl_xor(v, off);
    if (lane == 0) S_part[lt * 1536 + b * LYn + j0 + jw + jj] = v;
  }
}

// ---------------------------------------------------------------- kernel 3
// qtm: 2-product + register-prefetch staging; normalizes rows:
// out[j,f] = rcp(S_j) * sum_l e_jl * x_lf   (S_j = sum of 6 S_part slices).
__global__ __launch_bounds__(256) void qtm(
    const unsigned short* __restrict__ ahi,
    const unsigned short* __restrict__ xTh, const unsigned short* __restrict__ xTl,
    const float* __restrict__ S_part, float* __restrict__ out)
{
  __shared__ char smem[27648];
  __shared__ float Sr[64];
  unsigned short* LAh = (unsigned short*)smem;   // [64][72]
  unsigned short* LBh = LAh + 64 * 72;
  unsigned short* LBl = LBh + 64 * 72;

  const int bid = blockIdx.x;
  const int b = bid / 48, t = bid % 48;
  const int m0 = (t % 6) * 64, n0 = (t / 6) * 64;
  const int tid = threadIdx.x;
  const int r = tid >> 2, kq = (tid & 3) * 16;
  const int w = tid >> 6, lane = tid & 63, quad = lane >> 4, l15 = lane & 15;
  const int mo = (w & 1) * 32, no = (w >> 1) * 32;
  f32x4 acc[2][2] = {};

  if (tid < 64) {                       // row denominators (visible after 1st sync)
    int rw = b * LYn + m0 + tid;
    float s = S_part[rw] + S_part[1536 + rw] + S_part[3072 + rw]
            + S_part[4608 + rw] + S_part[6144 + rw] + S_part[7680 + rw];
    Sr[tid] = __builtin_amdgcn_rcpf(s);
  }

  const unsigned short* Arh = ahi + ((size_t)(b * LYn + m0 + r)) * LXn + kq;
  const unsigned short* Brh = xTh + ((size_t)(b * Fn + n0 + r)) * LXn + kq;
  const unsigned short* Brl = xTl + ((size_t)(b * Fn + n0 + r)) * LXn + kq;
  uint4 pA0 = *(const uint4*)(Arh),     pA1 = *(const uint4*)(Arh + 8);
  uint4 pH0 = *(const uint4*)(Brh),     pH1 = *(const uint4*)(Brh + 8);
  uint4 pL0 = *(const uint4*)(Brl),     pL1 = *(const uint4*)(Brl + 8);

  for (int kc = 0; kc < LXn; kc += 64) {
    __syncthreads();
    *(uint4*)&LAh[r * 72 + kq]     = pA0;  *(uint4*)&LAh[r * 72 + kq + 8] = pA1;
    *(uint4*)&LBh[r * 72 + kq]     = pH0;  *(uint4*)&LBh[r * 72 + kq + 8] = pH1;
    *(uint4*)&LBl[r * 72 + kq]     = pL0;  *(uint4*)&LBl[r * 72 + kq + 8] = pL1;
    __syncthreads();
    if (kc + 64 < LXn) {                  // prefetch next tile
      pA0 = *(const uint4*)(Arh + kc + 64); pA1 = *(const uint4*)(Arh + kc + 72);
      pH0 = *(const uint4*)(Brh + kc + 64); pH1 = *(const uint4*)(Brh + kc + 72);
      pL0 = *(const uint4*)(Brl + kc + 64); pL1 = *(const uint4*)(Brl + kc + 72);
    }
    #pragma unroll
    for (int ko = 0; ko < 64; ko += 32) {
      bf16x8 ah[2], bh[2], bl[2];
      #pragma unroll
      for (int mi = 0; mi < 2; ++mi)
        ah[mi] = *(const bf16x8*)&LAh[(mo + mi * 16 + l15) * 72 + ko + quad * 8];
      #pragma unroll
      for (int nj = 0; nj < 2; ++nj) {
        int rb = (no + nj * 16 + l15) * 72 + ko + quad * 8;
        bh[nj] = *(const bf16x8*)&LBh[rb]; bl[nj] = *(const bf16x8*)&LBl[rb];
      }
      #pragma unroll
      for (int mi = 0; mi < 2; ++mi)
        #pragma unroll
        for (int nj = 0; nj < 2; ++nj) {
          acc[mi][nj] = __builtin_amdgcn_mfma_f32_16x16x32_bf16(ah[mi], bh[nj], acc[mi][nj], 0, 0, 0);
          acc[mi][nj] = __builtin_amdgcn_mfma_f32_16x16x32_bf16(ah[mi], bl[nj], acc[mi][nj], 0, 0, 0);
        }
    }
  }
  #pragma unroll
  for (int mi = 0; mi < 2; ++mi)
    #pragma unroll
    for (int nj = 0; nj < 2; ++nj) {
      int lrow = mo + mi * 16 + quad * 4;
      #pragma unroll
      for (int rr = 0; rr < 4; ++rr) {
        int row = m0 + lrow + rr;
        int col = n0 + no + nj * 16 + l15;
        out[((size_t)(b * LYn + row)) * Fn + col] = acc[mi][nj][rr] * Sr[lrow + rr];
      }
    }
}

extern "C" void kernel_launch(void* const* d_in, const int* in_sizes, int n_in,
                              void* d_out, int out_size, void* d_ws, size_t ws_size,
                              hipStream_t stream) {
  const float* x  = (const float*)d_in[0];
  const float* y  = (const float*)d_in[1];
  const float* Wm = (const float*)d_in[2];
  const float* vm = (const float*)d_in[3];
  float* outp = (float*)d_out;

  float* ey  = (float*)d_ws;                              // 393216 f32
  float* exT = ey + 393216;                               // 393216 f32
  unsigned short* xTh = (unsigned short*)(exT + 393216);  // 786432 us
  unsigned short* xTl = xTh + 786432;
  unsigned short* ahi = xTl + 786432;                     // 589824 us
  float* S_part = (float*)(ahi + 589824);                 // 6*1536 f32

  hipLaunchKernelGGL(gemm5, dim3(576), dim3(256), 0, stream, x, y, Wm, ey, exT, xTh, xTl);
  hipLaunchKernelGGL(score_v6, dim3(384), dim3(512), 0, stream, exT, ey, vm, ahi, S_part);
  hipLaunchKernelGGL(qtm, dim3(192), dim3(256), 0, stream, ahi, xTh, xTl, S_part, outp);
}

// Round 6
// 106.135 us; speedup vs baseline: 1.0169x; 1.0169x over previous
//
#include <hip/hip_runtime.h>

#define LOG2E 1.4426950408889634f
#define K_SCALE 2.8853900817779268f   // 2*log2(e)

typedef __attribute__((ext_vector_type(8))) short bf16x8;
typedef __attribute__((ext_vector_type(4))) float f32x4;

constexpr int Bn = 4, LXn = 384, LYn = 384, Hn = 256, Fn = 512;

__device__ inline unsigned short bf16rn(float f) {
  unsigned u = __builtin_bit_cast(unsigned, f);
  u += 0x7fff + ((u >> 16) & 1);             // round-to-nearest-even
  return (unsigned short)(u >> 16);
}
__device__ inline float bf16tof(unsigned short h) {
  return __builtin_bit_cast(float, (unsigned)h << 16);
}

// ---------------------------------------------------------------- kernel 1
// (R12 gemm5 — correctness proven; single barrier per kc via LDS dbuf)
// blocks [0,192):   ey tiles 32x64  = exp2(-K * y.Wm^T)
// blocks [192,384): exT tiles 32x64 = exp2(+K * Wm.x^T)
// blocks [384,576): transpose+split x -> xTh/xTl[b][f][l]
__global__ __launch_bounds__(256) void gemm5(
    const float* __restrict__ x, const float* __restrict__ y,
    const float* __restrict__ Wm, float* __restrict__ ey, float* __restrict__ exT,
    unsigned short* __restrict__ xTh, unsigned short* __restrict__ xTl)
{
  __shared__ char smem[55296];
  const int tid = threadIdx.x;
  const int bid = blockIdx.x;

  if (bid >= 384) {                       // ---- transpose/split path ----
    float* T = (float*)smem;              // [64][65]
    const int pid = bid - 384;
    const int b = pid / 48, t = pid % 48;
    const int l0 = (t / 8) * 64, f0 = (t % 8) * 64;
    const int r = tid >> 2, cq = (tid & 3) * 16;
    const float* xp = x + ((size_t)(b * LXn + l0 + r)) * Fn + f0 + cq;
    #pragma unroll
    for (int q = 0; q < 4; ++q) {
      float4 v = *(const float4*)(xp + q * 4);
      T[r * 65 + cq + q * 4 + 0] = v.x; T[r * 65 + cq + q * 4 + 1] = v.y;
      T[r * 65 + cq + q * 4 + 2] = v.z; T[r * 65 + cq + q * 4 + 3] = v.w;
    }
    __syncthreads();
    const int fr = tid >> 2, lq = (tid & 3) * 16;
    unsigned short hi[16], lo[16];
    #pragma unroll
    for (int i = 0; i < 16; ++i) {
      float v = T[(lq + i) * 65 + fr];
      hi[i] = bf16rn(v);
      lo[i] = bf16rn(v - bf16tof(hi[i]));
    }
    size_t o = ((size_t)(b * Fn + f0 + fr)) * LXn + l0 + lq;
    *(uint4*)&xTh[o] = *(uint4*)&hi[0]; *(uint4*)&xTh[o + 8] = *(uint4*)&hi[8];
    *(uint4*)&xTl[o] = *(uint4*)&lo[0]; *(uint4*)&xTl[o + 8] = *(uint4*)&lo[8];
    return;
  }

  // ---- MFMA GEMM path, 32x64 tile, double-buffered ----
  unsigned short* S0 = (unsigned short*)smem;

  const float *Ap, *Bp; float ksc; bool jobA;
  int m0, n0;
  if (bid < 192) { jobA = true;  m0 = (bid % 48) * 32; n0 = (bid / 48) * 64;
                   Ap = y;  Bp = Wm; ksc = -K_SCALE; }
  else { int t = bid - 192; jobA = false; m0 = (t % 8) * 32; n0 = (t / 8) * 64;
                   Ap = Wm; Bp = x;  ksc =  K_SCALE; }

  const int rA = tid >> 3, kA = (tid & 7) * 8;    // A staging: 32 rows x 64 k
  const int rB = tid >> 2, kB = (tid & 3) * 16;   // B staging: 64 rows x 64 k
  const int w = tid >> 6, lane = tid & 63, quad = lane >> 4, l15 = lane & 15;
  const int mo = (w & 1) * 16, no = (w >> 1) * 32;   // wave: 16x32 out
  f32x4 acc[2] = {};

  const float* apt = Ap + ((size_t)(m0 + rA)) * Fn + kA;
  const float* bpt = Bp + ((size_t)(n0 + rB)) * Fn + kB;
  float4 aR0 = *(const float4*)(apt),     aR1 = *(const float4*)(apt + 4);
  float4 bR0 = *(const float4*)(bpt),     bR1 = *(const float4*)(bpt + 4);
  float4 bR2 = *(const float4*)(bpt + 8), bR3 = *(const float4*)(bpt + 12);

  // preload buffer 0
  {
    unsigned short* D = S0;
    float av[8] = {aR0.x, aR0.y, aR0.z, aR0.w, aR1.x, aR1.y, aR1.z, aR1.w};
    unsigned short hi[16], lo[16];
    #pragma unroll
    for (int i = 0; i < 8; ++i) { hi[i] = bf16rn(av[i]); lo[i] = bf16rn(av[i] - bf16tof(hi[i])); }
    *(uint4*)&D[rA * 72 + kA] = *(uint4*)&hi[0];
    *(uint4*)&D[2304 + rA * 72 + kA] = *(uint4*)&lo[0];
    float bv[16] = {bR0.x, bR0.y, bR0.z, bR0.w, bR1.x, bR1.y, bR1.z, bR1.w,
                    bR2.x, bR2.y, bR2.z, bR2.w, bR3.x, bR3.y, bR3.z, bR3.w};
    #pragma unroll
    for (int i = 0; i < 16; ++i) { hi[i] = bf16rn(bv[i]); lo[i] = bf16rn(bv[i] - bf16tof(hi[i])); }
    *(uint4*)&D[4608 + rB * 72 + kB] = *(uint4*)&hi[0];
    *(uint4*)&D[4608 + rB * 72 + kB + 8] = *(uint4*)&hi[8];
    *(uint4*)&D[9216 + rB * 72 + kB] = *(uint4*)&lo[0];
    *(uint4*)&D[9216 + rB * 72 + kB + 8] = *(uint4*)&lo[8];
  }
  __syncthreads();

  for (int kc = 0; kc < Fn; kc += 64) {
    const int cur = (kc >> 6) & 1;
    unsigned short* Sc = S0 + cur * 13824;
    unsigned short* Sn = S0 + (cur ^ 1) * 13824;
    const bool more = (kc + 64) < Fn;
    if (more) {                           // prefetch next tile into VGPRs
      aR0 = *(const float4*)(apt + kc + 64);     aR1 = *(const float4*)(apt + kc + 68);
      bR0 = *(const float4*)(bpt + kc + 64);     bR1 = *(const float4*)(bpt + kc + 68);
      bR2 = *(const float4*)(bpt + kc + 72);     bR3 = *(const float4*)(bpt + kc + 76);
    }
    #pragma unroll
    for (int ko = 0; ko < 64; ko += 32) {
      const int ra = (mo + l15) * 72 + ko + quad * 8;
      bf16x8 a_h = *(const bf16x8*)&Sc[ra];
      bf16x8 a_l = *(const bf16x8*)&Sc[2304 + ra];
      #pragma unroll
      for (int nj = 0; nj < 2; ++nj) {
        const int rb = (no + nj * 16 + l15) * 72 + ko + quad * 8;
        bf16x8 b_h = *(const bf16x8*)&Sc[4608 + rb];
        bf16x8 b_l = *(const bf16x8*)&Sc[9216 + rb];
        acc[nj] = __builtin_amdgcn_mfma_f32_16x16x32_bf16(a_h, b_h, acc[nj], 0, 0, 0);
        acc[nj] = __builtin_amdgcn_mfma_f32_16x16x32_bf16(a_l, b_h, acc[nj], 0, 0, 0);
        acc[nj] = __builtin_amdgcn_mfma_f32_16x16x32_bf16(a_h, b_l, acc[nj], 0, 0, 0);
      }
    }
    if (more) {                           // convert + store into idle buffer
      float av[8] = {aR0.x, aR0.y, aR0.z, aR0.w, aR1.x, aR1.y, aR1.z, aR1.w};
      unsigned short hi[16], lo[16];
      #pragma unroll
      for (int i = 0; i < 8; ++i) { hi[i] = bf16rn(av[i]); lo[i] = bf16rn(av[i] - bf16tof(hi[i])); }
      *(uint4*)&Sn[rA * 72 + kA] = *(uint4*)&hi[0];
      *(uint4*)&Sn[2304 + rA * 72 + kA] = *(uint4*)&lo[0];
      float bv[16] = {bR0.x, bR0.y, bR0.z, bR0.w, bR1.x, bR1.y, bR1.z, bR1.w,
                      bR2.x, bR2.y, bR2.z, bR2.w, bR3.x, bR3.y, bR3.z, bR3.w};
      #pragma unroll
      for (int i = 0; i < 16; ++i) { hi[i] = bf16rn(bv[i]); lo[i] = bf16rn(bv[i] - bf16tof(hi[i])); }
      *(uint4*)&Sn[4608 + rB * 72 + kB] = *(uint4*)&hi[0];
      *(uint4*)&Sn[4608 + rB * 72 + kB + 8] = *(uint4*)&hi[8];
      *(uint4*)&Sn[9216 + rB * 72 + kB] = *(uint4*)&lo[0];
      *(uint4*)&Sn[9216 + rB * 72 + kB + 8] = *(uint4*)&lo[8];
    }
    __syncthreads();                      // single barrier per kc
  }
  #pragma unroll
  for (int nj = 0; nj < 2; ++nj)
    #pragma unroll
    for (int rr = 0; rr < 4; ++rr) {
      int row = m0 + mo + quad * 4 + rr;
      int col = n0 + no + nj * 16 + l15;
      float val = __builtin_amdgcn_exp2f(ksc * acc[nj][rr]);
      if (jobA) ey[(size_t)row * Hn + col] = val;
      else {
        int bb = col / LXn, l = col % LXn;
        exT[(size_t)bb * Hn * LXn + (size_t)row * LXn + l] = val;
      }
    }
}

// ---------------------------------------------------------------- kernel 2
// score_v7: wave-aligned h-split. 512 thr = 8 waves; lane = l (64 l's),
// wave w owns h in [w*32, w*32+32). e read DIRECT from global (coalesced
// b32, L2-resident via XCD pinning) — no per-k LDS re-reads (v6's mistake).
// ey via wave-uniform b128 broadcast per (s,j). Fold = 2 aligned phases
// (8->4 planes, 4 adds) + 4-way final sum. ~50 KB LDS, ~50 VGPR ->
// 3 blocks/CU capacity at grid 384 -> barriers covered by co-residents.
// Writes unnormalized e (bf16) + S_part[6][b*384+j]; qtm normalizes.
__global__ __launch_bounds__(512) void score_v7(
    const float* __restrict__ exT, const float* __restrict__ ey,
    const float* __restrict__ vm, unsigned short* __restrict__ ahi,
    float* __restrict__ S_part)
{
  __shared__ __align__(16) float eyS[24 * 260];   // 25.0 KB
  __shared__ __align__(16) float vms[256];        // 1 KB
  __shared__ __align__(16) float part[4 * 24 * 64]; // 24.6 KB

  const int tid = threadIdx.x;
  const int bid = blockIdx.x;
  const int xcd = bid & 7, r = bid >> 3;        // XCD-pinned groups
  const int gslot = r % 3, jt = r / 3;
  const int g = gslot * 8 + xcd;                // 24 (b,lt) groups
  const int b = g / 6, lt = g % 6;
  const int j0 = jt * 24, l0 = lt * 64;

  // stage ey [24][256] (pad 260) and vms = -2*vm
  #pragma unroll
  for (int u = 0; u < 3; ++u) {
    int idx = tid + u * 512;                    // [0,1536) float4s
    int j = idx >> 6, q = idx & 63;
    float4 v = *(const float4*)&ey[(size_t)(b * LYn + j0 + j) * Hn + q * 4];
    *(float4*)&eyS[j * 260 + q * 4] = v;
  }
  if (tid < 64) {
    float4 v = *(const float4*)&vm[tid * 4];
    v.x *= -2.f; v.y *= -2.f; v.z *= -2.f; v.w *= -2.f;
    *(float4*)&vms[tid * 4] = v;
  }
  __syncthreads();

  const int lane = tid & 63, w = tid >> 6;      // 8 waves
  const float* exb = exT + (size_t)b * Hn * LXn + (size_t)(w * 32) * LXn + l0 + lane;

  float acc[24];
  #pragma unroll
  for (int j = 0; j < 24; ++j) acc[j] = 0.f;

  for (int s = 0; s < 8; ++s) {                 // 4 h per step, 32 h per wave
    float x0 = exb[(size_t)(s * 4 + 0) * LXn];
    float x1 = exb[(size_t)(s * 4 + 1) * LXn];
    float x2 = exb[(size_t)(s * 4 + 2) * LXn];
    float x3 = exb[(size_t)(s * 4 + 3) * LXn];
    const int k = w * 8 + s;                    // global h-quad index
    float4 va = *(const float4*)&vms[k * 4];
    #pragma unroll
    for (int j = 0; j < 24; ++j) {
      float4 ya = *(const float4*)&eyS[j * 260 + k * 4];
      float A = fmaf(x0, ya.x, 1.f);
      float B = fmaf(x1, ya.y, 1.f);
      float C = fmaf(x2, ya.z, 1.f);
      float D = fmaf(x3, ya.w, 1.f);
      float AB = A * B, CD = C * D;
      float n1 = fmaf(va.y, A, va.x * B);
      float n2 = fmaf(va.w, C, va.z * D);
      float num = fmaf(n2, AB, n1 * CD);
      acc[j] = fmaf(num, __builtin_amdgcn_rcpf(AB * CD), acc[j]);
    }
  }

  // fold 8 wave-planes -> 4 (aligned: whole waves active)
  if (w >= 4) {
    #pragma unroll
    for (int j = 0; j < 24; ++j)
      part[((w - 4) * 24 + j) * 64 + lane] = acc[j];
  }
  __syncthreads();
  if (w < 4) {
    #pragma unroll
    for (int j = 0; j < 24; ++j)
      part[(w * 24 + j) * 64 + lane] += acc[j];
  }
  __syncthreads();

  // epilogue: each thread 3 j's at fixed lane; e = exp2(s*log2e); wave-
  // reduce per-j partial row sums over this block's 64 l's.
  #pragma unroll
  for (int u = 0; u < 3; ++u) {
    const int j = w + u * 8;
    float sv = part[(0 * 24 + j) * 64 + lane] + part[(1 * 24 + j) * 64 + lane]
             + part[(2 * 24 + j) * 64 + lane] + part[(3 * 24 + j) * 64 + lane];
    float e = __builtin_amdgcn_exp2f(sv * LOG2E);
    ahi[(size_t)(b * LYn + j0 + j) * LXn + l0 + lane] = bf16rn(e);
    float v = e;
    #pragma unroll
    for (int off = 32; off > 0; off >>= 1) v += __shfl_xor(v, off);
    if (lane == 0) S_part[lt * 1536 + b * LYn + j0 + j] = v;
  }
}

// ---------------------------------------------------------------- kernel 3
// qtm: 2-product + register-prefetch staging; normalizes rows:
// out[j,f] = rcp(S_j) * sum_l e_jl * x_lf   (S_j = sum of 6 S_part slices).
__global__ __launch_bounds__(256) void qtm(
    const unsigned short* __restrict__ ahi,
    const unsigned short* __restrict__ xTh, const unsigned short* __restrict__ xTl,
    const float* __restrict__ S_part, float* __restrict__ out)
{
  __shared__ char smem[27648];
  __shared__ float Sr[64];
  unsigned short* LAh = (unsigned short*)smem;   // [64][72]
  unsigned short* LBh = LAh + 64 * 72;
  unsigned short* LBl = LBh + 64 * 72;

  const int bid = blockIdx.x;
  const int b = bid / 48, t = bid % 48;
  const int m0 = (t % 6) * 64, n0 = (t / 6) * 64;
  const int tid = threadIdx.x;
  const int r = tid >> 2, kq = (tid & 3) * 16;
  const int w = tid >> 6, lane = tid & 63, quad = lane >> 4, l15 = lane & 15;
  const int mo = (w & 1) * 32, no = (w >> 1) * 32;
  f32x4 acc[2][2] = {};

  if (tid < 64) {                       // row denominators (visible after 1st sync)
    int rw = b * LYn + m0 + tid;
    float s = S_part[rw] + S_part[1536 + rw] + S_part[3072 + rw]
            + S_part[4608 + rw] + S_part[6144 + rw] + S_part[7680 + rw];
    Sr[tid] = __builtin_amdgcn_rcpf(s);
  }

  const unsigned short* Arh = ahi + ((size_t)(b * LYn + m0 + r)) * LXn + kq;
  const unsigned short* Brh = xTh + ((size_t)(b * Fn + n0 + r)) * LXn + kq;
  const unsigned short* Brl = xTl + ((size_t)(b * Fn + n0 + r)) * LXn + kq;
  uint4 pA0 = *(const uint4*)(Arh),     pA1 = *(const uint4*)(Arh + 8);
  uint4 pH0 = *(const uint4*)(Brh),     pH1 = *(const uint4*)(Brh + 8);
  uint4 pL0 = *(const uint4*)(Brl),     pL1 = *(const uint4*)(Brl + 8);

  for (int kc = 0; kc < LXn; kc += 64) {
    __syncthreads();
    *(uint4*)&LAh[r * 72 + kq]     = pA0;  *(uint4*)&LAh[r * 72 + kq + 8] = pA1;
    *(uint4*)&LBh[r * 72 + kq]     = pH0;  *(uint4*)&LBh[r * 72 + kq + 8] = pH1;
    *(uint4*)&LBl[r * 72 + kq]     = pL0;  *(uint4*)&LBl[r * 72 + kq + 8] = pL1;
    __syncthreads();
    if (kc + 64 < LXn) {                  // prefetch next tile
      pA0 = *(const uint4*)(Arh + kc + 64); pA1 = *(const uint4*)(Arh + kc + 72);
      pH0 = *(const uint4*)(Brh + kc + 64); pH1 = *(const uint4*)(Brh + kc + 72);
      pL0 = *(const uint4*)(Brl + kc + 64); pL1 = *(const uint4*)(Brl + kc + 72);
    }
    #pragma unroll
    for (int ko = 0; ko < 64; ko += 32) {
      bf16x8 ah[2], bh[2], bl[2];
      #pragma unroll
      for (int mi = 0; mi < 2; ++mi)
        ah[mi] = *(const bf16x8*)&LAh[(mo + mi * 16 + l15) * 72 + ko + quad * 8];
      #pragma unroll
      for (int nj = 0; nj < 2; ++nj) {
        int rb = (no + nj * 16 + l15) * 72 + ko + quad * 8;
        bh[nj] = *(const bf16x8*)&LBh[rb]; bl[nj] = *(const bf16x8*)&LBl[rb];
      }
      #pragma unroll
      for (int mi = 0; mi < 2; ++mi)
        #pragma unroll
        for (int nj = 0; nj < 2; ++nj) {
          acc[mi][nj] = __builtin_amdgcn_mfma_f32_16x16x32_bf16(ah[mi], bh[nj], acc[mi][nj], 0, 0, 0);
          acc[mi][nj] = __builtin_amdgcn_mfma_f32_16x16x32_bf16(ah[mi], bl[nj], acc[mi][nj], 0, 0, 0);
        }
    }
  }
  #pragma unroll
  for (int mi = 0; mi < 2; ++mi)
    #pragma unroll
    for (int nj = 0; nj < 2; ++nj) {
      int lrow = mo + mi * 16 + quad * 4;
      #pragma unroll
      for (int rr = 0; rr < 4; ++rr) {
        int row = m0 + lrow + rr;
        int col = n0 + no + nj * 16 + l15;
        out[((size_t)(b * LYn + row)) * Fn + col] = acc[mi][nj][rr] * Sr[lrow + rr];
      }
    }
}

extern "C" void kernel_launch(void* const* d_in, const int* in_sizes, int n_in,
                              void* d_out, int out_size, void* d_ws, size_t ws_size,
                              hipStream_t stream) {
  const float* x  = (const float*)d_in[0];
  const float* y  = (const float*)d_in[1];
  const float* Wm = (const float*)d_in[2];
  const float* vm = (const float*)d_in[3];
  float* outp = (float*)d_out;

  float* ey  = (float*)d_ws;                              // 393216 f32
  float* exT = ey + 393216;                               // 393216 f32
  unsigned short* xTh = (unsigned short*)(exT + 393216);  // 786432 us
  unsigned short* xTl = xTh + 786432;
  unsigned short* ahi = xTl + 786432;                     // 589824 us
  float* S_part = (float*)(ahi + 589824);                 // 6*1536 f32

  hipLaunchKernelGGL(gemm5, dim3(576), dim3(256), 0, stream, x, y, Wm, ey, exT, xTh, xTl);
  hipLaunchKernelGGL(score_v7, dim3(384), dim3(512), 0, stream, exT, ey, vm, ahi, S_part);
  hipLaunchKernelGGL(qtm, dim3(192), dim3(256), 0, stream, ahi, xTh, xTl, S_part, outp);
}

// Round 7
// 99.708 us; speedup vs baseline: 1.0825x; 1.0645x over previous
//
#include <hip/hip_runtime.h>

#define LOG2E 1.4426950408889634f
#define K_SCALE 2.8853900817779268f   // 2*log2(e)

typedef __attribute__((ext_vector_type(8))) short bf16x8;
typedef __attribute__((ext_vector_type(4))) float f32x4;

constexpr int Bn = 4, LXn = 384, LYn = 384, Hn = 256, Fn = 512;

__device__ inline unsigned short bf16rn(float f) {
  unsigned u = __builtin_bit_cast(unsigned, f);
  u += 0x7fff + ((u >> 16) & 1);             // round-to-nearest-even
  return (unsigned short)(u >> 16);
}
__device__ inline float bf16tof(unsigned short h) {
  return __builtin_bit_cast(float, (unsigned)h << 16);
}

// ---------------------------------------------------------------- kernel 1
// (R12 gemm5 — correctness proven; single barrier per kc via LDS dbuf)
// blocks [0,192):   ey tiles 32x64  = exp2(-K * y.Wm^T)
// blocks [192,384): exT tiles 32x64 = exp2(+K * Wm.x^T)
// blocks [384,576): transpose+split x -> xTh/xTl[b][f][l]
__global__ __launch_bounds__(256) void gemm5(
    const float* __restrict__ x, const float* __restrict__ y,
    const float* __restrict__ Wm, float* __restrict__ ey, float* __restrict__ exT,
    unsigned short* __restrict__ xTh, unsigned short* __restrict__ xTl)
{
  __shared__ char smem[55296];
  const int tid = threadIdx.x;
  const int bid = blockIdx.x;

  if (bid >= 384) {                       // ---- transpose/split path ----
    float* T = (float*)smem;              // [64][65]
    const int pid = bid - 384;
    const int b = pid / 48, t = pid % 48;
    const int l0 = (t / 8) * 64, f0 = (t % 8) * 64;
    const int r = tid >> 2, cq = (tid & 3) * 16;
    const float* xp = x + ((size_t)(b * LXn + l0 + r)) * Fn + f0 + cq;
    #pragma unroll
    for (int q = 0; q < 4; ++q) {
      float4 v = *(const float4*)(xp + q * 4);
      T[r * 65 + cq + q * 4 + 0] = v.x; T[r * 65 + cq + q * 4 + 1] = v.y;
      T[r * 65 + cq + q * 4 + 2] = v.z; T[r * 65 + cq + q * 4 + 3] = v.w;
    }
    __syncthreads();
    const int fr = tid >> 2, lq = (tid & 3) * 16;
    unsigned short hi[16], lo[16];
    #pragma unroll
    for (int i = 0; i < 16; ++i) {
      float v = T[(lq + i) * 65 + fr];
      hi[i] = bf16rn(v);
      lo[i] = bf16rn(v - bf16tof(hi[i]));
    }
    size_t o = ((size_t)(b * Fn + f0 + fr)) * LXn + l0 + lq;
    *(uint4*)&xTh[o] = *(uint4*)&hi[0]; *(uint4*)&xTh[o + 8] = *(uint4*)&hi[8];
    *(uint4*)&xTl[o] = *(uint4*)&lo[0]; *(uint4*)&xTl[o + 8] = *(uint4*)&lo[8];
    return;
  }

  // ---- MFMA GEMM path, 32x64 tile, double-buffered ----
  unsigned short* S0 = (unsigned short*)smem;

  const float *Ap, *Bp; float ksc; bool jobA;
  int m0, n0;
  if (bid < 192) { jobA = true;  m0 = (bid % 48) * 32; n0 = (bid / 48) * 64;
                   Ap = y;  Bp = Wm; ksc = -K_SCALE; }
  else { int t = bid - 192; jobA = false; m0 = (t % 8) * 32; n0 = (t / 8) * 64;
                   Ap = Wm; Bp = x;  ksc =  K_SCALE; }

  const int rA = tid >> 3, kA = (tid & 7) * 8;    // A staging: 32 rows x 64 k
  const int rB = tid >> 2, kB = (tid & 3) * 16;   // B staging: 64 rows x 64 k
  const int w = tid >> 6, lane = tid & 63, quad = lane >> 4, l15 = lane & 15;
  const int mo = (w & 1) * 16, no = (w >> 1) * 32;   // wave: 16x32 out
  f32x4 acc[2] = {};

  const float* apt = Ap + ((size_t)(m0 + rA)) * Fn + kA;
  const float* bpt = Bp + ((size_t)(n0 + rB)) * Fn + kB;
  float4 aR0 = *(const float4*)(apt),     aR1 = *(const float4*)(apt + 4);
  float4 bR0 = *(const float4*)(bpt),     bR1 = *(const float4*)(bpt + 4);
  float4 bR2 = *(const float4*)(bpt + 8), bR3 = *(const float4*)(bpt + 12);

  // preload buffer 0
  {
    unsigned short* D = S0;
    float av[8] = {aR0.x, aR0.y, aR0.z, aR0.w, aR1.x, aR1.y, aR1.z, aR1.w};
    unsigned short hi[16], lo[16];
    #pragma unroll
    for (int i = 0; i < 8; ++i) { hi[i] = bf16rn(av[i]); lo[i] = bf16rn(av[i] - bf16tof(hi[i])); }
    *(uint4*)&D[rA * 72 + kA] = *(uint4*)&hi[0];
    *(uint4*)&D[2304 + rA * 72 + kA] = *(uint4*)&lo[0];
    float bv[16] = {bR0.x, bR0.y, bR0.z, bR0.w, bR1.x, bR1.y, bR1.z, bR1.w,
                    bR2.x, bR2.y, bR2.z, bR2.w, bR3.x, bR3.y, bR3.z, bR3.w};
    #pragma unroll
    for (int i = 0; i < 16; ++i) { hi[i] = bf16rn(bv[i]); lo[i] = bf16rn(bv[i] - bf16tof(hi[i])); }
    *(uint4*)&D[4608 + rB * 72 + kB] = *(uint4*)&hi[0];
    *(uint4*)&D[4608 + rB * 72 + kB + 8] = *(uint4*)&hi[8];
    *(uint4*)&D[9216 + rB * 72 + kB] = *(uint4*)&lo[0];
    *(uint4*)&D[9216 + rB * 72 + kB + 8] = *(uint4*)&lo[8];
  }
  __syncthreads();

  for (int kc = 0; kc < Fn; kc += 64) {
    const int cur = (kc >> 6) & 1;
    unsigned short* Sc = S0 + cur * 13824;
    unsigned short* Sn = S0 + (cur ^ 1) * 13824;
    const bool more = (kc + 64) < Fn;
    if (more) {                           // prefetch next tile into VGPRs
      aR0 = *(const float4*)(apt + kc + 64);     aR1 = *(const float4*)(apt + kc + 68);
      bR0 = *(const float4*)(bpt + kc + 64);     bR1 = *(const float4*)(bpt + kc + 68);
      bR2 = *(const float4*)(bpt + kc + 72);     bR3 = *(const float4*)(bpt + kc + 76);
    }
    #pragma unroll
    for (int ko = 0; ko < 64; ko += 32) {
      const int ra = (mo + l15) * 72 + ko + quad * 8;
      bf16x8 a_h = *(const bf16x8*)&Sc[ra];
      bf16x8 a_l = *(const bf16x8*)&Sc[2304 + ra];
      #pragma unroll
      for (int nj = 0; nj < 2; ++nj) {
        const int rb = (no + nj * 16 + l15) * 72 + ko + quad * 8;
        bf16x8 b_h = *(const bf16x8*)&Sc[4608 + rb];
        bf16x8 b_l = *(const bf16x8*)&Sc[9216 + rb];
        acc[nj] = __builtin_amdgcn_mfma_f32_16x16x32_bf16(a_h, b_h, acc[nj], 0, 0, 0);
        acc[nj] = __builtin_amdgcn_mfma_f32_16x16x32_bf16(a_l, b_h, acc[nj], 0, 0, 0);
        acc[nj] = __builtin_amdgcn_mfma_f32_16x16x32_bf16(a_h, b_l, acc[nj], 0, 0, 0);
      }
    }
    if (more) {                           // convert + store into idle buffer
      float av[8] = {aR0.x, aR0.y, aR0.z, aR0.w, aR1.x, aR1.y, aR1.z, aR1.w};
      unsigned short hi[16], lo[16];
      #pragma unroll
      for (int i = 0; i < 8; ++i) { hi[i] = bf16rn(av[i]); lo[i] = bf16rn(av[i] - bf16tof(hi[i])); }
      *(uint4*)&Sn[rA * 72 + kA] = *(uint4*)&hi[0];
      *(uint4*)&Sn[2304 + rA * 72 + kA] = *(uint4*)&lo[0];
      float bv[16] = {bR0.x, bR0.y, bR0.z, bR0.w, bR1.x, bR1.y, bR1.z, bR1.w,
                      bR2.x, bR2.y, bR2.z, bR2.w, bR3.x, bR3.y, bR3.z, bR3.w};
      #pragma unroll
      for (int i = 0; i < 16; ++i) { hi[i] = bf16rn(bv[i]); lo[i] = bf16rn(bv[i] - bf16tof(hi[i])); }
      *(uint4*)&Sn[4608 + rB * 72 + kB] = *(uint4*)&hi[0];
      *(uint4*)&Sn[4608 + rB * 72 + kB + 8] = *(uint4*)&hi[8];
      *(uint4*)&Sn[9216 + rB * 72 + kB] = *(uint4*)&lo[0];
      *(uint4*)&Sn[9216 + rB * 72 + kB + 8] = *(uint4*)&lo[8];
    }
    __syncthreads();                      // single barrier per kc
  }
  #pragma unroll
  for (int nj = 0; nj < 2; ++nj)
    #pragma unroll
    for (int rr = 0; rr < 4; ++rr) {
      int row = m0 + mo + quad * 4 + rr;
      int col = n0 + no + nj * 16 + l15;
      float val = __builtin_amdgcn_exp2f(ksc * acc[nj][rr]);
      if (jobA) ey[(size_t)row * Hn + col] = val;
      else {
        int bb = col / LXn, l = col % LXn;
        exT[(size_t)bb * Hn * LXn + (size_t)row * LXn + l] = val;
      }
    }
}

// ---------------------------------------------------------------- kernel 2
// score_v8: v7's verified structure rescaled to a BALANCED grid.
// J=12, L=64 -> grid = 4b x 6lt x 32jt = 768 blocks = exactly 3/CU,
// 512 thr = 8 waves; lane = l, wave w owns h in [w*32, w*32+32).
// ~26 KB LDS -> 3 co-resident blocks/CU (barriers covered, no idle CUs —
// v7's 1.5 blocks/CU imbalance was the 30 µs). XCD pinning: per-XCD exT
// working set = 3 x 64 KB = 192 KB -> L2-resident.
// Writes unnormalized e (bf16) + S_part[6][b*384+j]; qtm normalizes.
__global__ __launch_bounds__(512) void score_v8(
    const float* __restrict__ exT, const float* __restrict__ ey,
    const float* __restrict__ vm, unsigned short* __restrict__ ahi,
    float* __restrict__ S_part)
{
  __shared__ __align__(16) float eyS[12 * 260];     // 12.2 KB
  __shared__ __align__(16) float vms[256];          // 1 KB
  __shared__ __align__(16) float part[4 * 12 * 64]; // 12.3 KB

  const int tid = threadIdx.x;
  const int bid = blockIdx.x;
  const int xcd = bid & 7, r = bid >> 3;        // r in [0,96)
  const int gslot = r % 3, jt = r / 3;          // jt in [0,32)
  const int g = gslot * 8 + xcd;                // 24 (b,lt) groups
  const int b = g / 6, lt = g % 6;
  const int j0 = jt * 12, l0 = lt * 64;

  // stage ey [12][256] (pad 260) and vms = -2*vm
  {
    int j = tid >> 6, q = tid & 63;             // 512 of 768 float4s
    float4 v = *(const float4*)&ey[(size_t)(b * LYn + j0 + j) * Hn + q * 4];
    *(float4*)&eyS[j * 260 + q * 4] = v;
    if (tid < 256) {
      int idx = tid + 512; j = idx >> 6; q = idx & 63;
      v = *(const float4*)&ey[(size_t)(b * LYn + j0 + j) * Hn + q * 4];
      *(float4*)&eyS[j * 260 + q * 4] = v;
    }
  }
  if (tid < 64) {
    float4 v = *(const float4*)&vm[tid * 4];
    v.x *= -2.f; v.y *= -2.f; v.z *= -2.f; v.w *= -2.f;
    *(float4*)&vms[tid * 4] = v;
  }
  __syncthreads();

  const int lane = tid & 63, w = tid >> 6;      // 8 waves
  const float* exb = exT + (size_t)b * Hn * LXn + (size_t)(w * 32) * LXn + l0 + lane;

  float acc[12];
  #pragma unroll
  for (int j = 0; j < 12; ++j) acc[j] = 0.f;

  for (int s = 0; s < 8; ++s) {                 // 4 h per step, 32 h per wave
    float x0 = exb[(size_t)(s * 4 + 0) * LXn];
    float x1 = exb[(size_t)(s * 4 + 1) * LXn];
    float x2 = exb[(size_t)(s * 4 + 2) * LXn];
    float x3 = exb[(size_t)(s * 4 + 3) * LXn];
    const int k = w * 8 + s;                    // global h-quad index
    float4 va = *(const float4*)&vms[k * 4];
    #pragma unroll
    for (int j = 0; j < 12; ++j) {
      float4 ya = *(const float4*)&eyS[j * 260 + k * 4];
      float A = fmaf(x0, ya.x, 1.f);
      float B = fmaf(x1, ya.y, 1.f);
      float C = fmaf(x2, ya.z, 1.f);
      float D = fmaf(x3, ya.w, 1.f);
      float AB = A * B, CD = C * D;
      float n1 = fmaf(va.y, A, va.x * B);
      float n2 = fmaf(va.w, C, va.z * D);
      float num = fmaf(n2, AB, n1 * CD);
      acc[j] = fmaf(num, __builtin_amdgcn_rcpf(AB * CD), acc[j]);
    }
  }

  // fold 8 wave-planes -> 4 (aligned: whole waves active)
  if (w >= 4) {
    #pragma unroll
    for (int j = 0; j < 12; ++j)
      part[((w - 4) * 12 + j) * 64 + lane] = acc[j];
  }
  __syncthreads();
  if (w < 4) {
    #pragma unroll
    for (int j = 0; j < 12; ++j)
      part[(w * 12 + j) * 64 + lane] += acc[j];
  }
  __syncthreads();

  // epilogue: e = exp2(s*log2e); write bf16 e; wave-reduce row partial sums
  #pragma unroll
  for (int u = 0; u < 2; ++u) {
    const int j = w + u * 8;
    if (j < 12) {
      float sv = part[(0 * 12 + j) * 64 + lane] + part[(1 * 12 + j) * 64 + lane]
               + part[(2 * 12 + j) * 64 + lane] + part[(3 * 12 + j) * 64 + lane];
      float e = __builtin_amdgcn_exp2f(sv * LOG2E);
      ahi[(size_t)(b * LYn + j0 + j) * LXn + l0 + lane] = bf16rn(e);
      float v = e;
      #pragma unroll
      for (int off = 32; off > 0; off >>= 1) v += __shfl_xor(v, off);
      if (lane == 0) S_part[lt * 1536 + b * LYn + j0 + j] = v;
    }
  }
}

// ---------------------------------------------------------------- kernel 3
// qtm: 2-product + register-prefetch staging; normalizes rows:
// out[j,f] = rcp(S_j) * sum_l e_jl * x_lf   (S_j = sum of 6 S_part slices).
__global__ __launch_bounds__(256) void qtm(
    const unsigned short* __restrict__ ahi,
    const unsigned short* __restrict__ xTh, const unsigned short* __restrict__ xTl,
    const float* __restrict__ S_part, float* __restrict__ out)
{
  __shared__ char smem[27648];
  __shared__ float Sr[64];
  unsigned short* LAh = (unsigned short*)smem;   // [64][72]
  unsigned short* LBh = LAh + 64 * 72;
  unsigned short* LBl = LBh + 64 * 72;

  const int bid = blockIdx.x;
  const int b = bid / 48, t = bid % 48;
  const int m0 = (t % 6) * 64, n0 = (t / 6) * 64;
  const int tid = threadIdx.x;
  const int r = tid >> 2, kq = (tid & 3) * 16;
  const int w = tid >> 6, lane = tid & 63, quad = lane >> 4, l15 = lane & 15;
  const int mo = (w & 1) * 32, no = (w >> 1) * 32;
  f32x4 acc[2][2] = {};

  if (tid < 64) {                       // row denominators (visible after 1st sync)
    int rw = b * LYn + m0 + tid;
    float s = S_part[rw] + S_part[1536 + rw] + S_part[3072 + rw]
            + S_part[4608 + rw] + S_part[6144 + rw] + S_part[7680 + rw];
    Sr[tid] = __builtin_amdgcn_rcpf(s);
  }

  const unsigned short* Arh = ahi + ((size_t)(b * LYn + m0 + r)) * LXn + kq;
  const unsigned short* Brh = xTh + ((size_t)(b * Fn + n0 + r)) * LXn + kq;
  const unsigned short* Brl = xTl + ((size_t)(b * Fn + n0 + r)) * LXn + kq;
  uint4 pA0 = *(const uint4*)(Arh),     pA1 = *(const uint4*)(Arh + 8);
  uint4 pH0 = *(const uint4*)(Brh),     pH1 = *(const uint4*)(Brh + 8);
  uint4 pL0 = *(const uint4*)(Brl),     pL1 = *(const uint4*)(Brl + 8);

  for (int kc = 0; kc < LXn; kc += 64) {
    __syncthreads();
    *(uint4*)&LAh[r * 72 + kq]     = pA0;  *(uint4*)&LAh[r * 72 + kq + 8] = pA1;
    *(uint4*)&LBh[r * 72 + kq]     = pH0;  *(uint4*)&LBh[r * 72 + kq + 8] = pH1;
    *(uint4*)&LBl[r * 72 + kq]     = pL0;  *(uint4*)&LBl[r * 72 + kq + 8] = pL1;
    __syncthreads();
    if (kc + 64 < LXn) {                  // prefetch next tile
      pA0 = *(const uint4*)(Arh + kc + 64); pA1 = *(const uint4*)(Arh + kc + 72);
      pH0 = *(const uint4*)(Brh + kc + 64); pH1 = *(const uint4*)(Brh + kc + 72);
      pL0 = *(const uint4*)(Brl + kc + 64); pL1 = *(const uint4*)(Brl + kc + 72);
    }
    #pragma unroll
    for (int ko = 0; ko < 64; ko += 32) {
      bf16x8 ah[2], bh[2], bl[2];
      #pragma unroll
      for (int mi = 0; mi < 2; ++mi)
        ah[mi] = *(const bf16x8*)&LAh[(mo + mi * 16 + l15) * 72 + ko + quad * 8];
      #pragma unroll
      for (int nj = 0; nj < 2; ++nj) {
        int rb = (no + nj * 16 + l15) * 72 + ko + quad * 8;
        bh[nj] = *(const bf16x8*)&LBh[rb]; bl[nj] = *(const bf16x8*)&LBl[rb];
      }
      #pragma unroll
      for (int mi = 0; mi < 2; ++mi)
        #pragma unroll
        for (int nj = 0; nj < 2; ++nj) {
          acc[mi][nj] = __builtin_amdgcn_mfma_f32_16x16x32_bf16(ah[mi], bh[nj], acc[mi][nj], 0, 0, 0);
          acc[mi][nj] = __builtin_amdgcn_mfma_f32_16x16x32_bf16(ah[mi], bl[nj], acc[mi][nj], 0, 0, 0);
        }
    }
  }
  #pragma unroll
  for (int mi = 0; mi < 2; ++mi)
    #pragma unroll
    for (int nj = 0; nj < 2; ++nj) {
      int lrow = mo + mi * 16 + quad * 4;
      #pragma unroll
      for (int rr = 0; rr < 4; ++rr) {
        int row = m0 + lrow + rr;
        int col = n0 + no + nj * 16 + l15;
        out[((size_t)(b * LYn + row)) * Fn + col] = acc[mi][nj][rr] * Sr[lrow + rr];
      }
    }
}

extern "C" void kernel_launch(void* const* d_in, const int* in_sizes, int n_in,
                              void* d_out, int out_size, void* d_ws, size_t ws_size,
                              hipStream_t stream) {
  const float* x  = (const float*)d_in[0];
  const float* y  = (const float*)d_in[1];
  const float* Wm = (const float*)d_in[2];
  const float* vm = (const float*)d_in[3];
  float* outp = (float*)d_out;

  float* ey  = (float*)d_ws;                              // 393216 f32
  float* exT = ey + 393216;                               // 393216 f32
  unsigned short* xTh = (unsigned short*)(exT + 393216);  // 786432 us
  unsigned short* xTl = xTh + 786432;
  unsigned short* ahi = xTl + 786432;                     // 589824 us
  float* S_part = (float*)(ahi + 589824);                 // 6*1536 f32

  hipLaunchKernelGGL(gemm5, dim3(576), dim3(256), 0, stream, x, y, Wm, ey, exT, xTh, xTl);
  hipLaunchKernelGGL(score_v8, dim3(768), dim3(512), 0, stream, exT, ey, vm, ahi, S_part);
  hipLaunchKernelGGL(qtm, dim3(192), dim3(256), 0, stream, ahi, xTh, xTl, S_part, outp);
}